// Round 3
// baseline (145.938 us; speedup 1.0000x reference)
//
#include <hip/hip_runtime.h>
#include <math.h>

#define E_TOTAL 32768
#define NUM_NODES 4096
#define SCALE 0.70710678118654752f

typedef __attribute__((ext_vector_type(8))) short bfrag;
typedef __attribute__((ext_vector_type(16))) float facc;

__device__ inline unsigned short f2bf(float f) {
  unsigned int u = __float_as_uint(f);
  unsigned int r = (u + 0x7FFFu + ((u >> 16) & 1u)) >> 16;
  return (unsigned short)r;
}
__device__ inline float bf2f(unsigned short s) {
  return __uint_as_float(((unsigned int)s) << 16);
}
__device__ inline void cvt8(const float* v, bfrag& hi, bfrag& lo) {
#pragma unroll
  for (int i = 0; i < 8; ++i) {
    unsigned short h = f2bf(v[i]);
    hi[i] = (short)h;
    lo[i] = (short)f2bf(v[i] - bf2f(h));
  }
}

// async global->LDS, 16 B per lane, wave-uniform LDS base + lane*16
__device__ inline void stage16(const void* g, void* l) {
  __builtin_amdgcn_global_load_lds(
      (const __attribute__((address_space(1))) unsigned int*)g,
      (__attribute__((address_space(3))) unsigned int*)l, 16, 0, 0);
}

// ---------------------------------------------------------------------------
// Combined prep: blocks 0..95 W_p frags, 96..102 W_q frags, 103..230 offsets
// frag layout per n-tile nt=c*6+w: [ks(4)][hl(2)][lane(64)][j(8)] bf16 (8 KB)
//   element = W_p[d][w*512 + c*32 + (lane&31)], d = ks*16 + (lane>>5)*8 + j
// ---------------------------------------------------------------------------
__global__ __launch_bounds__(256) void prep_kernel(
    const float* __restrict__ Wp, const float* __restrict__ Wq,
    const int* __restrict__ index,
    unsigned short* __restrict__ fragWp, unsigned short* __restrict__ fragWq,
    int* __restrict__ offs)
{
  const int b = blockIdx.x, t = threadIdx.x;
  if (b < 96) {
    __shared__ unsigned short lds[4096];
    const int c = b / 6, w = b - c * 6;
    const int colbase = w * 512 + c * 32;
    const int cl = t & 31, dg = t >> 5;
#pragma unroll
    for (int i = 0; i < 8; ++i) {
      const int d = dg * 8 + i;
      const float v = Wp[(size_t)d * 3072 + colbase + cl];
      const unsigned short hi = f2bf(v);
      const unsigned short lo = f2bf(v - bf2f(hi));
      const int ks = d >> 4;
      const int lane = ((d >> 3) & 1) * 32 + cl;
      const int j = d & 7;
      lds[(ks * 2 + 0) * 512 + lane * 8 + j] = hi;
      lds[(ks * 2 + 1) * 512 + lane * 8 + j] = lo;
    }
    __syncthreads();
    unsigned short* dst = fragWp + (size_t)b * 4096;
    ((uint4*)dst)[t] = ((const uint4*)lds)[t];
    ((uint4*)dst)[t + 256] = ((const uint4*)lds)[t + 256];
  } else if (b < 103) {
    const int slot = b - 96;
    const int w = (slot == 6) ? 5 : slot;
    const float sgn = (slot == 6) ? -1.f : 1.f;
    for (int tt = t; tt < 512; tt += 256) {
      const int lane = tt >> 3, j = tt & 7;
      const int o = lane & 31, c = (lane >> 5) * 8 + j;
      const float v = sgn * Wq[(size_t)(w * 16 + c) * 32 + o];
      const unsigned short hi = f2bf(v);
      const unsigned short lo = f2bf(v - bf2f(hi));
      fragWq[slot * 1024 + lane * 8 + j] = hi;
      fragWq[slot * 1024 + 512 + lane * 8 + j] = lo;
    }
  } else {
    const int tg = (b - 103) * 256 + t;
    if (tg >= E_TOTAL) return;
    const int cur = index[tg];
    const int prev = (tg == 0) ? -1 : index[tg - 1];
    for (int n = prev + 1; n <= cur; ++n) offs[n] = tg;
    if (tg == E_TOTAL - 1)
      for (int n = cur + 1; n <= NUM_NODES; ++n) offs[n] = E_TOTAL;
  }
}

// ---------------------------------------------------------------------------
// Main: 256 blocks (1/CU), 4 waves, 128 edges/block, 32 edges/wave.
// The 3 MB/CU fragWp stream was global-pipe-bound (~26 B/cyc/CU, invariant
// across rounds 0-2). Now each 8 KB tile is staged into LDS ONCE per block
// (global_load_lds x2/wave, double-buffered, 1 barrier/tile); the 4x re-read
// runs on the LDS pipe (~85-128 B/cyc/CU). Per tile: G=8 KB (async-hidden),
// L=32 KB (~384 cyc), MFMA+VALU ~230 cyc/SIMD hidden under other waves' LDS.
// Each wave's ka is COMPLETE -> no cross-wave reduce, no epilogue dup.
// ---------------------------------------------------------------------------
__global__ __launch_bounds__(256, 1) void main_kernel(
    const float* __restrict__ x_q, const float* __restrict__ x_k,
    const float* __restrict__ emb,
    const unsigned short* __restrict__ fragWp,
    const unsigned short* __restrict__ fragWq,
    float* __restrict__ z)
{
  __shared__ float xk_t[64][129];                   // 33 KB, padded
  __shared__ alignas(16) unsigned short wbuf[2][4096];  // 2 x 8 KB tile dbuf

  const int t = threadIdx.x;
  const int lane = t & 63, wv = t >> 6;
  const int col = lane & 31, half = lane >> 5;
  const int eb = blockIdx.x * 128;
  const int el = wv * 32 + col;
  const int e = eb + el;

  // stage x_k transposed: thread t -> edge t&127, d-half (t>>7)*32
  {
    const int er = t & 127, dh = (t >> 7) * 32;
    const float* src = x_k + (size_t)(eb + er) * 64 + dh;
#pragma unroll
    for (int i = 0; i < 8; ++i) {
      float4 v = *(const float4*)(src + i * 4);
      xk_t[dh + i * 4 + 0][er] = v.x;
      xk_t[dh + i * 4 + 1][er] = v.y;
      xk_t[dh + i * 4 + 2][er] = v.z;
      xk_t[dh + i * 4 + 3][er] = v.w;
    }
  }

  // prologue: stage tile 0 into wbuf[0] (2 chunks of 1 KB per wave)
  {
    const char* tb = (const char*)fragWp;
    char* db = (char*)&wbuf[0][0];
    stage16(tb + (wv * 2 + 0) * 1024 + lane * 16, db + (wv * 2 + 0) * 1024);
    stage16(tb + (wv * 2 + 1) * 1024 + lane * 16, db + (wv * 2 + 1) * 1024);
  }

  // emb B-fragments hi/lo for this wave's 32 edges: B[k=d][col=e]
  bfrag ebh[4], ebl[4];
#pragma unroll
  for (int ks = 0; ks < 4; ++ks) {
    float tmp[8];
    *(float4*)&tmp[0] = *(const float4*)(emb + (size_t)e * 64 + ks * 16 + half * 8);
    *(float4*)&tmp[4] = *(const float4*)(emb + (size_t)e * 64 + ks * 16 + half * 8 + 4);
    cvt8(tmp, ebh[ks], ebl[ks]);
  }

  facc ka0 = {0}, ka1 = {0}, ka2 = {0}, ka3 = {0};

  __syncthreads();  // xk_t ready + tile 0 staged (syncthreads drains vmcnt)

  float xkc0 = 0.f, xkc1 = 0.f, xkc2 = 0.f, xkc3 = 0.f;

  for (int ot = 0; ot < 16; ++ot) {
#pragma unroll
    for (int ii = 0; ii < 6; ++ii) {
      const int it = ot * 6 + ii;
      // issue async stage of tile it+1 into the other buffer (parity static)
      if (it != 95) {
        const char* tb = (const char*)fragWp + (size_t)(it + 1) * 8192;
        char* db = (char*)&wbuf[(ii + 1) & 1][0];
        stage16(tb + (wv * 2 + 0) * 1024 + lane * 16, db + (wv * 2 + 0) * 1024);
        stage16(tb + (wv * 2 + 1) * 1024 + lane * 16, db + (wv * 2 + 1) * 1024);
      }
      if (ii == 0) {
        xkc0 = xk_t[ot][el];
        xkc1 = xk_t[16 + ot][el];
        xkc2 = xk_t[32 + ot][el];
        xkc3 = xk_t[48 + ot][el];
      }
      // read this tile's 8 fragments from LDS (ds_read_b128, conflict-free)
      const unsigned short* wb = &wbuf[ii & 1][0];
      bfrag ch[4], cl4[4];
#pragma unroll
      for (int ks = 0; ks < 4; ++ks) {
        *(uint4*)&ch[ks]  = *(const uint4*)(wb + ks * 1024 + lane * 8);
        *(uint4*)&cl4[ks] = *(const uint4*)(wb + ks * 1024 + 512 + lane * 8);
      }
      facc cc0 = {0.f}, cc1 = {0.f}, cc2 = {0.f};  // 3 chains of 4 (ILP)
#pragma unroll
      for (int ks = 0; ks < 4; ++ks) {
        cc0 = __builtin_amdgcn_mfma_f32_32x32x16_bf16(ch[ks], ebh[ks], cc0, 0, 0, 0);
        cc1 = __builtin_amdgcn_mfma_f32_32x32x16_bf16(ch[ks], ebl[ks], cc1, 0, 0, 0);
        cc2 = __builtin_amdgcn_mfma_f32_32x32x16_bf16(cl4[ks], ebh[ks], cc2, 0, 0, 0);
      }
      // so2 contraction per w = ii:
      //   w0: x0->m0  w1: x0->m2  w2: x2->m0  w3: x2->m2
      //   w4: x1->m1, x3->m3      w5: x3->m1, -x1->m3
      if (ii < 4) {
        const float xv = (ii & 2) ? xkc2 : xkc0;
        facc& kd = (ii & 1) ? ka2 : ka0;
#pragma unroll
        for (int r = 0; r < 16; ++r)
          kd[r] = fmaf(xv, cc0[r] + cc1[r] + cc2[r], kd[r]);
      } else if (ii == 4) {
#pragma unroll
        for (int r = 0; r < 16; ++r) {
          const float s = cc0[r] + cc1[r] + cc2[r];
          ka1[r] = fmaf(xkc1, s, ka1[r]);
          ka3[r] = fmaf(xkc3, s, ka3[r]);
        }
      } else {
#pragma unroll
        for (int r = 0; r < 16; ++r) {
          const float s = cc0[r] + cc1[r] + cc2[r];
          ka1[r] = fmaf(xkc3, s, ka1[r]);
          ka3[r] = fmaf(-xkc1, s, ka3[r]);
        }
      }
      // barrier: stage of it+1 drained (vmcnt), all waves done reading wbuf[ii&1]
      __syncthreads();
    }
  }

  // ---- q via MFMA (same C layout as ka), full z per wave, direct store
  bfrag xqh[4], xql[4];
#pragma unroll
  for (int a = 0; a < 4; ++a) {
    float tmp[8];
    *(float4*)&tmp[0] = *(const float4*)(x_q + (size_t)e * 64 + a * 16 + half * 8);
    *(float4*)&tmp[4] = *(const float4*)(x_q + (size_t)e * 64 + a * 16 + half * 8 + 4);
    cvt8(tmp, xqh[a], xql[a]);
  }
  float zp0 = 0.f, zp1 = 0.f, zp2 = 0.f, zp3 = 0.f;
  const int QA1[4] = {0, 1, 0, 3}, QS1[4] = {0, 4, 1, 4};
  const int QA2[4] = {2, 3, 2, 1}, QS2[4] = {2, 5, 3, 6};  // slot 6 = -Wq[5]
#pragma unroll
  for (int m = 0; m < 4; ++m) {
    facc qa = {0.f};
#pragma unroll
    for (int tm = 0; tm < 2; ++tm) {
      const int a = tm ? QA2[m] : QA1[m];
      const int sl = tm ? QS2[m] : QS1[m];
      bfrag wh, wl;
      *(uint4*)&wh = *(const uint4*)(fragWq + sl * 1024 + lane * 8);
      *(uint4*)&wl = *(const uint4*)(fragWq + sl * 1024 + 512 + lane * 8);
      qa = __builtin_amdgcn_mfma_f32_32x32x16_bf16(wh, xqh[a], qa, 0, 0, 0);
      qa = __builtin_amdgcn_mfma_f32_32x32x16_bf16(wh, xql[a], qa, 0, 0, 0);
      qa = __builtin_amdgcn_mfma_f32_32x32x16_bf16(wl, xqh[a], qa, 0, 0, 0);
    }
    const facc& km = (m == 0) ? ka0 : (m == 1) ? ka1 : (m == 2) ? ka2 : ka3;
#pragma unroll
    for (int r = 0; r < 16; ++r) {
      const float v = qa[r] * km[r];
      if (r < 4) zp0 += v;
      else if (r < 8) zp1 += v;
      else if (r < 12) zp2 += v;
      else zp3 += v;
    }
  }
  zp0 += __shfl_xor(zp0, 32);
  zp1 += __shfl_xor(zp1, 32);
  zp2 += __shfl_xor(zp2, 32);
  zp3 += __shfl_xor(zp3, 32);
  if (half == 0) {
    float4 v = {zp0 * SCALE, zp1 * SCALE, zp2 * SCALE, zp3 * SCALE};
    *(float4*)&z[(size_t)e * 4] = v;
  }
}

// ---------------------------------------------------------------------------
__global__ __launch_bounds__(256) void softmax_kernel(
    const float* __restrict__ z, const int* __restrict__ offs,
    float* __restrict__ out)
{
  const int node = blockIdx.x * 4 + (threadIdx.x >> 6);
  const int lane = threadIdx.x & 63;
  const int start = offs[node], end = offs[node + 1];
  if (start >= end) return;
  const int h = lane & 3, eo = lane >> 2;
  float m = -INFINITY;
  for (int e = start + eo; e < end; e += 16) m = fmaxf(m, z[(size_t)e * 4 + h]);
#pragma unroll
  for (int s = 4; s < 64; s <<= 1) m = fmaxf(m, __shfl_xor(m, s));
  float sum = 0.f;
  for (int e = start + eo; e < end; e += 16) sum += __expf(z[(size_t)e * 4 + h] - m);
#pragma unroll
  for (int s = 4; s < 64; s <<= 1) sum += __shfl_xor(sum, s);
  const float inv = 1.f / sum;
  for (int e = start + eo; e < end; e += 16)
    out[(size_t)e * 4 + h] = __expf(z[(size_t)e * 4 + h] - m) * inv;
}

extern "C" void kernel_launch(void* const* d_in, const int* in_sizes, int n_in,
                              void* d_out, int out_size, void* d_ws, size_t ws_size,
                              hipStream_t stream) {
  const float* x_q = (const float*)d_in[0];
  const float* x_k = (const float*)d_in[1];
  const float* emb = (const float*)d_in[2];
  const int* index = (const int*)d_in[3];
  const float* W_q = (const float*)d_in[4];
  const float* W_p = (const float*)d_in[5];
  float* out = (float*)d_out;

  char* ws = (char*)d_ws;
  float* z = (float*)ws;                                                    // 524288 B
  int* offs = (int*)(ws + 524288);                                          // 16388 B (pad 32 KB)
  unsigned short* fragWp = (unsigned short*)(ws + 524288 + 32768);          // 786432 B
  unsigned short* fragWq = (unsigned short*)(ws + 524288 + 32768 + 786432); // 14336 B

  prep_kernel<<<231, 256, 0, stream>>>(W_p, W_q, index, fragWp, fragWq, offs);
  main_kernel<<<256, 256, 0, stream>>>(x_q, x_k, emb, fragWp, fragWq, z);
  softmax_kernel<<<1024, 256, 0, stream>>>(z, offs, out);
}